// Round 2
// baseline (2834.691 us; speedup 1.0000x reference)
//
#include <hip/hip_runtime.h>
#include <hip/hip_bf16.h>

#define BB 256
#define TT 512
#define XS 40
#define HS 128
#define GS 512  // 4*HS

enum { MODE_PROJ = 0, MODE_FLAT = 1, MODE_CONCAT = 2 };

__device__ __forceinline__ float fast_sigmoid(float x) {
    return __frcp_rn(1.0f + __expf(-x));
}
__device__ __forceinline__ float fast_tanh(float x) {
    x = fminf(fmaxf(x, -15.0f), 15.0f);
    float e = __expf(2.0f * x);
    return (e - 1.0f) * __frcp_rn(e + 1.0f);
}

// K-chunked fp32 GEMM, 128x64 tile, k-major LDS, 8x4 per-thread accumulator.
// out rows: PROJ -> local chunk row m; else m + ooff. A rows: PROJ -> (b,t0+tt)
// remap; FLAT/CONCAT -> m + t0. CONCAT: col<XS from A(x), else A2(y).
template <int K, int KC, int NS, int MODE, bool RELU>
__global__ __launch_bounds__(256) void gemm2(
    const float* __restrict__ A, const float* __restrict__ A2,
    const float* __restrict__ W, const float* __restrict__ b1p,
    const float* __restrict__ b2p, float* __restrict__ out,
    int Tc, int t0, int ooff) {
    __shared__ float at[KC][132];  // [k][m] transposed, pad keeps b128 align (132*4B=528=33*16)
    __shared__ float wt[KC][68];   // [k][n]
    const int tid = threadIdx.x;
    const int row0 = blockIdx.x * 128;
    const int n0 = blockIdx.y * 64;
    const int tx = tid & 15;   // n = n0 + tx*4 + j
    const int ty = tid >> 4;   // m = row0 + ty*8 + i

    float acc[8][4] = {};

    for (int c0 = 0; c0 < K; c0 += KC) {
        // stage A chunk (transposed) — consecutive lanes read consecutive cols
        for (int idx = tid; idx < 128 * KC; idx += 256) {
            int r = idx / KC, c = idx - r * KC;
            int cg = c0 + c;
            int m = row0 + r;
            float v;
            if (MODE == MODE_PROJ) {
                int b = m / Tc, tt = m - b * Tc;
                v = A[(size_t)(b * TT + t0 + tt) * K + cg];
            } else if (MODE == MODE_FLAT) {
                v = A[(size_t)(m + t0) * K + cg];
            } else {
                int mg = m + t0;
                v = (cg < XS) ? A[(size_t)mg * XS + cg] : A2[(size_t)mg * HS + (cg - XS)];
            }
            at[c][r] = v;
        }
        for (int idx = tid; idx < 64 * KC; idx += 256) {
            int r = idx / KC, c = idx - r * KC;
            wt[c][r] = W[(size_t)(n0 + r) * K + c0 + c];
        }
        __syncthreads();

#pragma unroll 4
        for (int k = 0; k < KC; ++k) {
            float4 a0 = *(const float4*)&at[k][ty * 8];
            float4 a1 = *(const float4*)&at[k][ty * 8 + 4];
            float4 wv = *(const float4*)&wt[k][tx * 4];
            float av[8] = {a0.x, a0.y, a0.z, a0.w, a1.x, a1.y, a1.z, a1.w};
            float wj[4] = {wv.x, wv.y, wv.z, wv.w};
#pragma unroll
            for (int i = 0; i < 8; i++)
#pragma unroll
                for (int j = 0; j < 4; j++) acc[i][j] = fmaf(av[i], wj[j], acc[i][j]);
        }
        __syncthreads();
    }

    float4 bv = *(const float4*)&b1p[n0 + tx * 4];
    if (MODE == MODE_PROJ) {
        float4 b2v = *(const float4*)&b2p[n0 + tx * 4];
        bv.x += b2v.x; bv.y += b2v.y; bv.z += b2v.z; bv.w += b2v.w;
    }
#pragma unroll
    for (int i = 0; i < 8; i++) {
        int m = row0 + ty * 8 + i;
        size_t obase = (MODE == MODE_PROJ) ? (size_t)m * NS : (size_t)(m + ooff) * NS;
        float4 o;
        o.x = acc[i][0] + bv.x; o.y = acc[i][1] + bv.y;
        o.z = acc[i][2] + bv.z; o.w = acc[i][3] + bv.w;
        if (RELU) {
            o.x = fmaxf(o.x, 0.f); o.y = fmaxf(o.y, 0.f);
            o.z = fmaxf(o.z, 0.f); o.w = fmaxf(o.w, 0.f);
        }
        *(float4*)&out[obase + n0 + tx * 4] = o;
    }
}

// One block per batch row; 1024 threads (16 waves -> 4/SIMD). Thread pair
// (gate, half) splits the 128-dot: 64 weights per thread in NAMED float4
// registers (64 VGPRs, fits 128-VGPR budget -> no reload from L2).
#define WLOAD(i) float4 w##i = wr[i];
#define DOT(i)                                    \
    {                                             \
        float4 hv = h4[i];                        \
        s0 = fmaf(w##i.x, hv.x, s0);              \
        s1 = fmaf(w##i.y, hv.y, s1);              \
        s2 = fmaf(w##i.z, hv.z, s2);              \
        s3 = fmaf(w##i.w, hv.w, s3);              \
    }

__global__ __launch_bounds__(1024, 4) void lstm_rec2(
    const float* __restrict__ Whh, const float* __restrict__ xW,
    const float* __restrict__ h0, const float* __restrict__ c0,
    float* __restrict__ hstate, float* __restrict__ cstate,
    float* __restrict__ y, int Tc, int t0) {
    const int b = blockIdx.x;
    const int tid = threadIdx.x;
    const int gate = tid >> 1;   // 0..511
    const int half = tid & 1;    // which 64-chunk of the dot
    __shared__ __align__(16) float h_sh[HS];
    __shared__ float act[GS];

    const float4* wr = (const float4*)(Whh + (size_t)gate * HS + half * 64);
    WLOAD(0) WLOAD(1) WLOAD(2) WLOAD(3) WLOAD(4) WLOAD(5) WLOAD(6) WLOAD(7)
    WLOAD(8) WLOAD(9) WLOAD(10) WLOAD(11) WLOAD(12) WLOAD(13) WLOAD(14) WLOAD(15)

    float c = 0.0f;
    if (tid < HS) {
        float hv;
        if (t0 == 0) {
            hv = h0[(size_t)b * HS + tid];
            c = c0[(size_t)b * HS + tid];
        } else {
            hv = hstate[(size_t)b * HS + tid];
            c = cstate[(size_t)b * HS + tid];
        }
        h_sh[tid] = hv;
    }
    __syncthreads();

    const float* xWrow = xW + (size_t)b * Tc * GS;
    float* yrow = y + ((size_t)b * TT + t0) * HS;
    const float4* h4 = (const float4*)h_sh + half * 16;
    const int gtype = gate >> 7;  // 0=i 1=f 2=g 3=o (wave-uniform: 4 waves per type)

    for (int t = 0; t < Tc; ++t) {
        float a = (half == 0) ? xWrow[(size_t)t * GS + gate] : 0.0f;
        float s0 = 0.f, s1 = 0.f, s2 = 0.f, s3 = 0.f;
        DOT(0) DOT(1) DOT(2) DOT(3) DOT(4) DOT(5) DOT(6) DOT(7)
        DOT(8) DOT(9) DOT(10) DOT(11) DOT(12) DOT(13) DOT(14) DOT(15)
        float v = (s0 + s1) + (s2 + s3);
        v += __shfl_xor(v, 1);  // partner lane holds other half of the dot
        if (half == 0) {
            v += a;
            act[gate] = (gtype == 2) ? fast_tanh(v) : fast_sigmoid(v);
        }
        __syncthreads();
        if (tid < HS) {
            float iv = act[tid], fv = act[HS + tid], gv = act[2 * HS + tid], ov = act[3 * HS + tid];
            c = fmaf(fv, c, iv * gv);
            float hv = ov * fast_tanh(c);
            h_sh[tid] = hv;
            yrow[(size_t)t * HS + tid] = hv;
        }
        __syncthreads();
    }
    if (tid < HS) {
        hstate[(size_t)b * HS + tid] = h_sh[tid];
        cstate[(size_t)b * HS + tid] = c;
    }
}

// out[row] = dot(z2[row,:], W3[0,:]) + b3 — one wave per row
__global__ __launch_bounds__(256) void head_dot(
    const float* __restrict__ z2, const float* __restrict__ W3,
    const float* __restrict__ b3, float* __restrict__ out) {
    const int wave = threadIdx.x >> 6, lane = threadIdx.x & 63;
    const int row = blockIdx.x * 4 + wave;
    const float* zr = z2 + (size_t)row * HS;
    float v = zr[lane] * W3[lane] + zr[64 + lane] * W3[64 + lane];
#pragma unroll
    for (int m = 32; m >= 1; m >>= 1) v += __shfl_xor(v, m, 64);
    if (lane == 0) out[row] = v + b3[0];
}

extern "C" void kernel_launch(void* const* d_in, const int* in_sizes, int n_in,
                              void* d_out, int out_size, void* d_ws, size_t ws_size,
                              hipStream_t stream) {
    const float* x = (const float*)d_in[0];
    const float* h0 = (const float*)d_in[1];
    const float* c0 = (const float*)d_in[2];
    const float* Wih[3] = {(const float*)d_in[3], (const float*)d_in[7], (const float*)d_in[11]};
    const float* Whh[3] = {(const float*)d_in[4], (const float*)d_in[8], (const float*)d_in[12]};
    const float* bih[3] = {(const float*)d_in[5], (const float*)d_in[9], (const float*)d_in[13]};
    const float* bhh[3] = {(const float*)d_in[6], (const float*)d_in[10], (const float*)d_in[14]};
    const float* W1 = (const float*)d_in[15];
    const float* b1 = (const float*)d_in[16];
    const float* W2 = (const float*)d_in[17];
    const float* b2 = (const float*)d_in[18];
    const float* W3 = (const float*)d_in[19];
    const float* b3 = (const float*)d_in[20];
    float* outp = (float*)d_out;

    // workspace layout: y[B,T,H] | xW[B,Tc,4H] | hstate[B,H] | cstate[B,H]
    int Tc = TT;
    while (Tc > 8) {
        size_t need = ((size_t)BB * TT * HS + (size_t)BB * Tc * GS + 2 * (size_t)BB * HS) * 4;
        if (need <= ws_size) break;
        Tc >>= 1;
    }
    float* yb = (float*)d_ws;
    float* xw = yb + (size_t)BB * TT * HS;
    float* hs = xw + (size_t)BB * Tc * GS;
    float* cs = hs + (size_t)BB * HS;

    for (int l = 0; l < 3; ++l) {
        for (int t0 = 0; t0 < TT; t0 += Tc) {
            dim3 gp(BB * Tc / 128, GS / 64);
            if (l == 0)
                gemm2<XS, XS, GS, MODE_PROJ, false><<<gp, 256, 0, stream>>>(
                    x, nullptr, Wih[0], bih[0], bhh[0], xw, Tc, t0, 0);
            else
                gemm2<HS, 32, GS, MODE_PROJ, false><<<gp, 256, 0, stream>>>(
                    yb, nullptr, Wih[l], bih[l], bhh[l], xw, Tc, t0, 0);
            lstm_rec2<<<BB, 1024, 0, stream>>>(Whh[l], xw,
                                               h0 + (size_t)l * BB * HS, c0 + (size_t)l * BB * HS,
                                               hs, cs, yb, Tc, t0);
        }
    }

    // MLP head, row-chunked: z1 (local rows) lives in xw buffer
    const int totalRows = BB * TT;
    int Rc = BB * Tc * (GS / HS);
    if (Rc > totalRows) Rc = totalRows;
    for (int r0 = 0; r0 < totalRows; r0 += Rc) {
        dim3 gm(Rc / 128, HS / 64);
        // z1[m] = relu(concat(x,y)[r0+m] . W1^T)  (A rows global, out rows local)
        gemm2<XS + HS, 28, HS, MODE_CONCAT, true><<<gm, 256, 0, stream>>>(
            x, yb, W1, b1, nullptr, xw, 0, r0, 0);
        // z2[r0+m] = relu(z1[m] . W2^T)  (A rows local, out rows global into yb)
        gemm2<HS, 32, HS, MODE_FLAT, true><<<gm, 256, 0, stream>>>(
            xw, nullptr, W2, b2, nullptr, yb, 0, 0, r0);
    }
    head_dot<<<totalRows / 4, 256, 0, stream>>>(yb, W3, b3, outp);
}